// Round 12
// baseline (260.180 us; speedup 1.0000x reference)
//
#include <hip/hip_runtime.h>

#define BATCH 256
#define NROW  512
#define CDIM  256
#define SPLIT 8
#define CHUNK (NROW / SPLIT)   // 64 rows per (b,s) block
#define WPB   4                // waves per block (256 threads)
#define RPW   (CHUNK / WPB)    // 16 rows per wave
#define CHK   8                // rows per register chunk (2 chunks, both prefetched)

#define DOT4(a, b) ((a).x * (b).x + (a).y * (b).y + (a).z * (b).z + (a).w * (b).w)

// ---------------------------------------------------------------------------
// K0 prep (96 blocks):
//  blocks 0-63 : MT[c][e] = sum_d Wq[d][c]*Wk[d][e], 4 c-rows per block.
//                block 0 also c0[e] = sum_d bq[d]*Wk[d][e].
//  blocks 64-95: WvT[c][d] = Wv[d][c], 8 d-rows per block.
// All inner loops unroll-8 (8 independent coalesced loads in flight).
// ---------------------------------------------------------------------------
__global__ __launch_bounds__(256) void prep_kernel(
    const float* __restrict__ Wq, const float* __restrict__ bq,
    const float* __restrict__ Wk, const float* __restrict__ Wv,
    float* __restrict__ MT, float* __restrict__ c0, float* __restrict__ WvT) {
  const int t = threadIdx.x;

  if (blockIdx.x < 64) {
    __shared__ float4 s_wq4[CDIM];  // s_wq4[d] = Wq[d][cbase..cbase+4)
    __shared__ float s_bq[CDIM];
    const int cbase = blockIdx.x * 4;
    // one-time uncoalesced stage (256 x 16B)
    s_wq4[t] = *(const float4*)(Wq + (size_t)t * CDIM + cbase);
    if (blockIdx.x == 0) s_bq[t] = bq[t];
    __syncthreads();

    float a0 = 0.f, a1 = 0.f, a2 = 0.f, a3 = 0.f, ac = 0.f;
#pragma unroll 8
    for (int d = 0; d < CDIM; ++d) {
      const float wkv = Wk[(size_t)d * CDIM + t];  // coalesced
      const float4 w4 = s_wq4[d];                  // LDS b128 broadcast
      a0 += w4.x * wkv; a1 += w4.y * wkv;
      a2 += w4.z * wkv; a3 += w4.w * wkv;
      if (blockIdx.x == 0) ac += s_bq[d] * wkv;    // uniform branch
    }
    MT[(size_t)(cbase + 0) * CDIM + t] = a0;
    MT[(size_t)(cbase + 1) * CDIM + t] = a1;
    MT[(size_t)(cbase + 2) * CDIM + t] = a2;
    MT[(size_t)(cbase + 3) * CDIM + t] = a3;
    if (blockIdx.x == 0) c0[t] = ac;
  } else {
    __shared__ float s_wv[8][CDIM + 1];
    const int rbase = (blockIdx.x - 64) * 8;
#pragma unroll
    for (int r = 0; r < 8; ++r)
      s_wv[r][t] = Wv[(size_t)(rbase + r) * CDIM + t];  // coalesced
    __syncthreads();
    // thread t writes WvT[t][rbase..rbase+8) as two float4s
    const float4 v0 =
        make_float4(s_wv[0][t], s_wv[1][t], s_wv[2][t], s_wv[3][t]);
    const float4 v1 =
        make_float4(s_wv[4][t], s_wv[5][t], s_wv[6][t], s_wv[7][t]);
    *(float4*)(WvT + (size_t)t * CDIM + rbase) = v0;
    *(float4*)(WvT + (size_t)t * CDIM + rbase + 4) = v1;
  }
}

// ---------------------------------------------------------------------------
// K1: qk[b,:] = MT^T-apply(psel[b]) + c0, 8 batches per block (32 blocks).
// Batches transposed into LDS [c][8] so the c-loop reads 2 x b128 broadcast
// + 1 coalesced MT row per iter; unroll-8 for MLP.
// Score term Q.bk is constant over n -> softmax-invariant -> dropped.
// ---------------------------------------------------------------------------
__global__ __launch_bounds__(256) void qk_kernel(
    const float* __restrict__ P, const int* __restrict__ idx,
    const float* __restrict__ MT, const float* __restrict__ c0,
    float* __restrict__ qk) {
  const int t = threadIdx.x;
  const int b0 = blockIdx.x * 8;

  __shared__ float s_psT[CDIM][8];  // [c][j]
#pragma unroll
  for (int j = 0; j < 8; ++j)
    s_psT[t][j] =
        P[((size_t)(b0 + j) * NROW + (size_t)idx[b0 + j]) * CDIM + t];
  __syncthreads();

  float acc[8] = {0.f, 0.f, 0.f, 0.f, 0.f, 0.f, 0.f, 0.f};
#pragma unroll 8
  for (int c = 0; c < CDIM; ++c) {
    const float mtv = MT[(size_t)c * CDIM + t];          // coalesced
    const float4 p0 = *(const float4*)&s_psT[c][0];      // b128 broadcast
    const float4 p1 = *(const float4*)&s_psT[c][4];
    acc[0] += p0.x * mtv; acc[1] += p0.y * mtv;
    acc[2] += p0.z * mtv; acc[3] += p0.w * mtv;
    acc[4] += p1.x * mtv; acc[5] += p1.y * mtv;
    acc[6] += p1.z * mtv; acc[7] += p1.w * mtv;
  }
  const float cc = c0[t];
#pragma unroll
  for (int j = 0; j < 8; ++j) qk[(size_t)(b0 + j) * CDIM + t] = acc[j] + cc;
}

// ---------------------------------------------------------------------------
// K2: per (b,s): online softmax + ctx partial over 64 rows. 2048 blocks.
// PROVEN 21.8us (R9 replicate measurement). Unchanged from round 8.
// ---------------------------------------------------------------------------
__global__ __launch_bounds__(256, 4) void attn_part_kernel(
    const float* __restrict__ P, const float* __restrict__ qk,
    float* __restrict__ ctxp, float* __restrict__ mp, float* __restrict__ lp) {
  const int bs = blockIdx.x;
  const int b = bs >> 3;
  const int s = bs & (SPLIT - 1);
  const int t = threadIdx.x;
  const int lane = t & 63;
  const int w = t >> 6;

  __shared__ float s_ctx[WPB][CDIM];
  __shared__ float s_m[WPB], s_l[WPB];

  const float* Pw =
      P + ((size_t)b * NROW + (size_t)s * CHUNK + (size_t)w * RPW) * CDIM;

  const float4 qk4 = ((const float4*)(qk + (size_t)b * CDIM))[lane];

  // issue ALL 16 rows' loads before any consume (max MLP)
  float4 pv0[CHK], pv1[CHK];
#pragma unroll
  for (int i = 0; i < CHK; ++i)
    pv0[i] = ((const float4*)(Pw + (size_t)i * CDIM))[lane];
#pragma unroll
  for (int i = 0; i < CHK; ++i)
    pv1[i] = ((const float4*)(Pw + (size_t)(CHK + i) * CDIM))[lane];

  float m = -1e30f, l = 0.f;
  float4 ctx = make_float4(0.f, 0.f, 0.f, 0.f);

#define CONSUME(cur)                                                         \
  {                                                                          \
    float sc[CHK];                                                           \
    _Pragma("unroll") for (int i = 0; i < CHK; ++i) {                        \
      float part = DOT4(cur[i], qk4);                                        \
      _Pragma("unroll") for (int mm = 32; mm >= 1; mm >>= 1)                 \
          part += __shfl_xor(part, mm, 64);                                  \
      sc[i] = part;                                                          \
    }                                                                        \
    float cmax = sc[0];                                                      \
    _Pragma("unroll") for (int i = 1; i < CHK; ++i)                          \
        cmax = fmaxf(cmax, sc[i]);                                           \
    const float mnew = fmaxf(m, cmax);                                       \
    const float scale = __expf(m - mnew); /* first iter: ~exp(-inf)=0 */     \
    l *= scale;                                                              \
    ctx.x *= scale; ctx.y *= scale; ctx.z *= scale; ctx.w *= scale;          \
    _Pragma("unroll") for (int i = 0; i < CHK; ++i) {                        \
      const float p = __expf(sc[i] - mnew);                                  \
      l += p;                                                                \
      ctx.x += p * cur[i].x; ctx.y += p * cur[i].y;                          \
      ctx.z += p * cur[i].z; ctx.w += p * cur[i].w;                          \
    }                                                                        \
    m = mnew;                                                                \
  }

  CONSUME(pv0);
  CONSUME(pv1);
#undef CONSUME

  ((float4*)s_ctx[w])[lane] = ctx;
  if (lane == 0) { s_m[w] = m; s_l[w] = l; }
  __syncthreads();

  const float mb = fmaxf(fmaxf(s_m[0], s_m[1]), fmaxf(s_m[2], s_m[3]));
  const float co0 = __expf(s_m[0] - mb), co1 = __expf(s_m[1] - mb);
  const float co2 = __expf(s_m[2] - mb), co3 = __expf(s_m[3] - mb);
  ctxp[(size_t)bs * CDIM + t] = co0 * s_ctx[0][t] + co1 * s_ctx[1][t] +
                                co2 * s_ctx[2][t] + co3 * s_ctx[3][t];
  if (t == 0) {
    mp[bs] = mb;
    lp[bs] = co0 * s_l[0] + co1 * s_l[1] + co2 * s_l[2] + co3 * s_l[3];
  }
}

// ---------------------------------------------------------------------------
// K3: merge 8 splits + out = WvT-apply(ctxn) + bv, 8 batches per block
// (32 blocks). ctxn transposed into LDS [c][8]; c-loop = 1 coalesced WvT row
// + 2 b128 broadcasts per iter, unroll-8.
// ---------------------------------------------------------------------------
__global__ __launch_bounds__(256) void combine_kernel(
    const float* __restrict__ ctxp, const float* __restrict__ mp,
    const float* __restrict__ lp, const float* __restrict__ WvT,
    const float* __restrict__ bv, float* __restrict__ out) {
  const int t = threadIdx.x;
  const int b0 = blockIdx.x * 8;

  __shared__ float s_cT[CDIM][8];  // [c][j]

#pragma unroll
  for (int j = 0; j < 8; ++j) {
    const int b = b0 + j;
    float ms[SPLIT];
    float mg = -3.4e38f;
#pragma unroll
    for (int i = 0; i < SPLIT; ++i) {
      ms[i] = mp[b * SPLIT + i];  // uniform -> scalar loads
      mg = fmaxf(mg, ms[i]);
    }
    float lg = 0.f, c = 0.f;
#pragma unroll
    for (int i = 0; i < SPLIT; ++i) {
      const float ww = __expf(ms[i] - mg);
      lg += lp[b * SPLIT + i] * ww;
      c += ctxp[(size_t)(b * SPLIT + i) * CDIM + t] * ww;  // coalesced
    }
    s_cT[t][j] = c / lg;
  }
  __syncthreads();

  float acc[8] = {0.f, 0.f, 0.f, 0.f, 0.f, 0.f, 0.f, 0.f};
#pragma unroll 8
  for (int c = 0; c < CDIM; ++c) {
    const float wvt = WvT[(size_t)c * CDIM + t];         // coalesced
    const float4 c0_ = *(const float4*)&s_cT[c][0];      // b128 broadcast
    const float4 c1_ = *(const float4*)&s_cT[c][4];
    acc[0] += c0_.x * wvt; acc[1] += c0_.y * wvt;
    acc[2] += c0_.z * wvt; acc[3] += c0_.w * wvt;
    acc[4] += c1_.x * wvt; acc[5] += c1_.y * wvt;
    acc[6] += c1_.z * wvt; acc[7] += c1_.w * wvt;
  }
  const float bvt = bv[t];
#pragma unroll
  for (int j = 0; j < 8; ++j) out[(size_t)(b0 + j) * CDIM + t] = acc[j] + bvt;
}

// ---------------------------------------------------------------------------
extern "C" void kernel_launch(void* const* d_in, const int* in_sizes, int n_in,
                              void* d_out, int out_size, void* d_ws,
                              size_t ws_size, hipStream_t stream) {
  const float* P  = (const float*)d_in[0];
  const int*  idx = (const int*)d_in[1];   // jax default x64-off: int32
  const float* Wq = (const float*)d_in[2];
  const float* bq = (const float*)d_in[3];
  const float* Wk = (const float*)d_in[4];
  // d_in[5] = bk: constant score shift per batch -> softmax-invariant -> unused
  const float* Wv = (const float*)d_in[6];
  const float* bv = (const float*)d_in[7];
  float* out = (float*)d_out;

  float* ws   = (float*)d_ws;
  float* MT   = ws;                            // 256*256
  float* c0   = MT + CDIM * CDIM;              // 256
  float* WvT  = c0 + CDIM;                     // 256*256
  float* qk   = WvT + CDIM * CDIM;             // B*C
  float* ctxp = qk + BATCH * CDIM;             // B*SPLIT*C = 2MB
  float* mp   = ctxp + BATCH * SPLIT * CDIM;   // B*SPLIT
  float* lp   = mp + BATCH * SPLIT;            // B*SPLIT

  prep_kernel<<<96, 256, 0, stream>>>(Wq, bq, Wk, Wv, MT, c0, WvT);
  qk_kernel<<<BATCH / 8, 256, 0, stream>>>(P, idx, MT, c0, qk);
  attn_part_kernel<<<BATCH * SPLIT, 256, 0, stream>>>(P, qk, ctxp, mp, lp);
  combine_kernel<<<BATCH / 8, 256, 0, stream>>>(ctxp, mp, lp, WvT, bv, out);
}